// Round 7
// baseline (2455.103 us; speedup 1.0000x reference)
//
#include <hip/hip_runtime.h>
#include <hip/hip_bf16.h>
#include <math.h>

// Problem constants
#define BB   4
#define SS   1024
#define VV   256
#define KDIM 64
#define HH   8
#define TT   4
#define EPSV 1e-3f
#define SCL  0.125f        // KD^-0.5
#define INV2048 4.8828125e-4f

typedef float f4 __attribute__((ext_vector_type(4)));
typedef short bf8 __attribute__((ext_vector_type(8)));       // 8 bf16
typedef _Float16 h8 __attribute__((ext_vector_type(8)));     // 8 f16
typedef _Float16 h4 __attribute__((ext_vector_type(4)));

#define LDP 68   // fp32 GEMM LDS stride (floats)
#define LHS 68   // f16/bf16 LDS stride (halves/shorts; 34 dwords -> 2-way, free)

__device__ __forceinline__ short f2bf(float x) {
  __hip_bfloat16 h = __float2bfloat16(x);   // RNE
  return *reinterpret_cast<short*>(&h);
}
__device__ __forceinline__ float bf2f(short h) {
  union { unsigned u; float f; } cv;
  cv.u = ((unsigned)(unsigned short)h) << 16;
  return cv.f;
}

// ---------------------------------------------------------------------------
// fp32 GEMM core (R4, proven) — used only by k_in_dense (1 dispatch).
// ---------------------------------------------------------------------------
__device__ __forceinline__ void gemm_core(
    const float* __restrict__ A, const float* __restrict__ Bm, int ldb,
    float acc[4][4], float (*As)[LDP], float (*Bs)[LDP])
{
  const int tid = threadIdx.x;
  const int tx = tid & 15, ty = tid >> 4;
#pragma unroll
  for (int i = 0; i < 4; i++)
#pragma unroll
    for (int j = 0; j < 4; j++) acc[i][j] = 0.f;

  for (int k0 = 0; k0 < 256; k0 += 16) {
#pragma unroll
    for (int l = 0; l < 4; l++) {
      int e = tid + l * 256;
      int r = e >> 4, kk = e & 15;
      As[kk][r] = A[r * 256 + k0 + kk];
      int rb = e >> 6, nn = e & 63;
      Bs[rb][nn] = Bm[(k0 + rb) * ldb + nn];
    }
    __syncthreads();
#pragma unroll
    for (int kk = 0; kk < 16; kk++) {
      f4 av = *(const f4*)&As[kk][ty * 4];
      f4 bv = *(const f4*)&Bs[kk][tx * 4];
#pragma unroll
      for (int i = 0; i < 4; i++)
#pragma unroll
        for (int j = 0; j < 4; j++)
          acc[i][j] += av[i] * bv[j];
    }
    __syncthreads();
  }
}

// ---------------------------------------------------------------------------
// net0 = x @ W_in, broadcast into all H head slots (R4 verbatim)
// ---------------------------------------------------------------------------
__global__ __launch_bounds__(256) void k_in_dense(
    const float* __restrict__ x, const float* __restrict__ Win,
    float* __restrict__ net)
{
  __shared__ __align__(16) float As[16][LDP];
  __shared__ __align__(16) float Bs[16][LDP];
  const int mt = blockIdx.x, nt = blockIdx.y;
  float acc[4][4];
  gemm_core(x + mt * 64 * 256, Win + nt * 64, 256, acc, As, Bs);
  const int tx = threadIdx.x & 15, ty = threadIdx.x >> 4;
#pragma unroll
  for (int i = 0; i < 4; i++) {
    f4 v;
#pragma unroll
    for (int j = 0; j < 4; j++) v[j] = acc[i][j];
    int row = mt * 64 + ty * 4 + i;
    int col = nt * 64 + tx * 4;
    for (int h = 0; h < HH; h++)
      *(f4*)&net[(size_t)h * 1048576 + row * 256 + col] = v;
  }
}

// ---------------------------------------------------------------------------
// Weight prep (R6 verbatim): transpose + split into f16 hi/lo, [n][k(256)].
// ---------------------------------------------------------------------------
__global__ __launch_bounds__(256) void k_prep(
    const float* __restrict__ Wq, const float* __restrict__ Wk,
    const float* __restrict__ Wv, const float* __restrict__ Wd,
    _Float16* __restrict__ oh, _Float16* __restrict__ ol, int t)
{
  __shared__ __align__(16) _Float16 Th[64][LHS];
  __shared__ __align__(16) _Float16 Tl[64][LHS];
  const int xb = blockIdx.x, kb = blockIdx.y, h = blockIdx.z;
  const int tid = threadIdx.x;
  const float* src; int N, nb; size_t dbase;
  if (xb == 0)      { src = Wq; N = 64;  nb = 0;      dbase = (size_t)h * 16384; }
  else if (xb == 1) { src = Wk; N = 64;  nb = 0;      dbase = 131072 + (size_t)h * 16384; }
  else if (xb < 6)  { src = Wv; N = 256; nb = xb - 2; dbase = 262144 + (size_t)h * 65536; }
  else              { src = Wd; N = 256; nb = xb - 6; dbase = 786432 + (size_t)h * 65536; }
  src += (size_t)(h * TT + t) * 256 * N;
#pragma unroll
  for (int i = 0; i < 4; i++) {
    int fi = tid + i * 256;
    int r = fi >> 4, c4 = fi & 15;
    f4 w = *(const f4*)&src[(size_t)(kb * 64 + r) * N + nb * 64 + c4 * 4];
    h4 hv, lv;
#pragma unroll
    for (int j = 0; j < 4; j++) {
      _Float16 hi = (_Float16)w[j];
      hv[j] = hi;
      lv[j] = (_Float16)((w[j] - (float)hi) * 2048.f);
    }
    *(h4*)&Th[r][c4 * 4] = hv;
    *(h4*)&Tl[r][c4 * 4] = lv;
  }
  __syncthreads();
#pragma unroll
  for (int i = 0; i < 4; i++) {
    int fo = tid + i * 256;
    int nr = fo >> 4, k4 = fo & 15;
    h4 hv, lv;
#pragma unroll
    for (int j = 0; j < 4; j++) { hv[j] = Th[k4 * 4 + j][nr]; lv[j] = Tl[k4 * 4 + j][nr]; }
    size_t d = dbase + (size_t)(nb * 64 + nr) * 256 + kb * 64 + k4 * 4;
    *(h4*)&oh[d] = hv;
    *(h4*)&ol[d] = lv;
  }
}

// ---------------------------------------------------------------------------
// Split-f16 MFMA GEMM core (R6 verbatim).
// ---------------------------------------------------------------------------
__device__ __forceinline__ void mm_core(
    const float* __restrict__ A,
    const _Float16* __restrict__ Bh, const _Float16* __restrict__ Bl,
    f4 cm[4], _Float16 (*Ah)[LHS], _Float16 (*Al)[LHS])
{
  const int tid = threadIdx.x, wv = tid >> 6, lane = tid & 63;
  const int ln = lane & 15, quad = lane >> 4;
  f4 mn[4], cr[4];
#pragma unroll
  for (int mf = 0; mf < 4; mf++) {
    mn[mf] = (f4){0.f, 0.f, 0.f, 0.f};
    cr[mf] = (f4){0.f, 0.f, 0.f, 0.f};
  }
  const _Float16* bhp = Bh + (size_t)(wv * 16 + ln) * 256;
  const _Float16* blp = Bl + (size_t)(wv * 16 + ln) * 256;

  for (int kc = 0; kc < 4; kc++) {
#pragma unroll
    for (int i = 0; i < 4; i++) {
      int fi = tid + i * 256;
      int r = fi >> 4, c4 = fi & 15;
      f4 w = *(const f4*)&A[(size_t)r * 256 + kc * 64 + c4 * 4];
      h4 hv, lv;
#pragma unroll
      for (int j = 0; j < 4; j++) {
        _Float16 hi = (_Float16)w[j];
        hv[j] = hi;
        lv[j] = (_Float16)((w[j] - (float)hi) * 2048.f);
      }
      *(h4*)&Ah[r][c4 * 4] = hv;
      *(h4*)&Al[r][c4 * 4] = lv;
    }
    h8 bh0 = *(const h8*)&bhp[kc * 64 + quad * 8];
    h8 bh1 = *(const h8*)&bhp[kc * 64 + 32 + quad * 8];
    h8 bl0 = *(const h8*)&blp[kc * 64 + quad * 8];
    h8 bl1 = *(const h8*)&blp[kc * 64 + 32 + quad * 8];
    __syncthreads();
#pragma unroll
    for (int mf = 0; mf < 4; mf++) {
      h8 ah0 = *(const h8*)&Ah[mf * 16 + ln][quad * 8];
      h8 ah1 = *(const h8*)&Ah[mf * 16 + ln][32 + quad * 8];
      h8 al0 = *(const h8*)&Al[mf * 16 + ln][quad * 8];
      h8 al1 = *(const h8*)&Al[mf * 16 + ln][32 + quad * 8];
      mn[mf] = __builtin_amdgcn_mfma_f32_16x16x32_f16(ah0, bh0, mn[mf], 0, 0, 0);
      mn[mf] = __builtin_amdgcn_mfma_f32_16x16x32_f16(ah1, bh1, mn[mf], 0, 0, 0);
      cr[mf] = __builtin_amdgcn_mfma_f32_16x16x32_f16(ah0, bl0, cr[mf], 0, 0, 0);
      cr[mf] = __builtin_amdgcn_mfma_f32_16x16x32_f16(ah1, bl1, cr[mf], 0, 0, 0);
      cr[mf] = __builtin_amdgcn_mfma_f32_16x16x32_f16(al0, bh0, cr[mf], 0, 0, 0);
      cr[mf] = __builtin_amdgcn_mfma_f32_16x16x32_f16(al1, bh1, cr[mf], 0, 0, 0);
    }
    __syncthreads();
  }
#pragma unroll
  for (int mf = 0; mf < 4; mf++)
#pragma unroll
    for (int r = 0; r < 4; r++)
      cm[mf][r] = mn[mf][r] + cr[mf][r] * INV2048;
}

// ---------------------------------------------------------------------------
// QKV GEMM: q/k -> f16 hi/lo ROW-MAJOR [h][4096][64] (for MFMA attn);
// v -> bf16 hi/lo transposed [h*4+b][vcol][s]. grid (64, 6, 8)
// ---------------------------------------------------------------------------
__global__ __launch_bounds__(256) void k_mm_qkv(
    const float* __restrict__ net,
    const _Float16* __restrict__ wph, const _Float16* __restrict__ wpl,
    _Float16* __restrict__ qhb, _Float16* __restrict__ qlb,
    _Float16* __restrict__ khb, _Float16* __restrict__ klb,
    short* __restrict__ vth, short* __restrict__ vtl)
{
  __shared__ __align__(16) _Float16 Ah[64][LHS];
  __shared__ __align__(16) _Float16 Al[64][LHS];
  const int mt = blockIdx.x, nt = blockIdx.y, h = blockIdx.z;
  const int tid = threadIdx.x, wv = tid >> 6, lane = tid & 63;
  const int ln = lane & 15, quad = lane >> 4;
  const float* A = net + (size_t)h * 1048576 + (size_t)mt * 64 * 256;
  size_t bbase;
  if (nt == 0)      bbase = (size_t)h * 16384;
  else if (nt == 1) bbase = 131072 + (size_t)h * 16384;
  else              bbase = 262144 + (size_t)h * 65536 + (size_t)(nt - 2) * 64 * 256;
  f4 cm[4];
  mm_core(A, wph + bbase, wpl + bbase, cm, Ah, Al);

  if (nt <= 1) {
    _Float16* hb = (nt == 0) ? qhb : khb;
    _Float16* lb = (nt == 0) ? qlb : klb;
    int col = wv * 16 + ln;
#pragma unroll
    for (int mf = 0; mf < 4; mf++)
#pragma unroll
      for (int r = 0; r < 4; r++) {
        int row = mt * 64 + mf * 16 + quad * 4 + r;
        float v = cm[mf][r];
        _Float16 hi = (_Float16)v;
        size_t base = ((size_t)h * 4096 + row) * 64 + col;
        hb[base] = hi;
        lb[base] = (_Float16)((v - (float)hi) * 2048.f);
      }
  } else {
    int c = (nt - 2) * 64 + wv * 16 + ln;
#pragma unroll
    for (int mf = 0; mf < 4; mf++)
#pragma unroll
      for (int r = 0; r < 4; r++) {
        int row = mt * 64 + mf * 16 + quad * 4 + r;
        int b_ = row >> 10, sI = row & 1023;
        float v = cm[mf][r];
        short hi = f2bf(v);
        size_t idx = ((size_t)(h * 4 + b_) * 256 + c) * 1024 + sI;
        vth[idx] = hi;
        vtl[idx] = f2bf(v - bf2f(hi));
      }
  }
}

// ---------------------------------------------------------------------------
// Dense GEMM: tmp = net + relu(net @ Wd), FUSED BN stats. grid (64, 4, 8)
// ---------------------------------------------------------------------------
__global__ __launch_bounds__(256) void k_mm_dense(
    const float* __restrict__ net,
    const _Float16* __restrict__ wph, const _Float16* __restrict__ wpl,
    float* __restrict__ tmp, float* __restrict__ stats)
{
  __shared__ __align__(16) _Float16 Ah[64][LHS];
  __shared__ __align__(16) _Float16 Al[64][LHS];
  const int mt = blockIdx.x, nt = blockIdx.y, h = blockIdx.z;
  const int tid = threadIdx.x, wv = tid >> 6, lane = tid & 63;
  const int ln = lane & 15, quad = lane >> 4;
  const float* A = net + (size_t)h * 1048576 + (size_t)mt * 64 * 256;
  size_t bbase = 786432 + (size_t)h * 65536 + (size_t)nt * 64 * 256;
  f4 cm[4];
  mm_core(A, wph + bbase, wpl + bbase, cm, Ah, Al);

  int col = nt * 64 + wv * 16 + ln;
  float cs = 0.f, cq = 0.f;
#pragma unroll
  for (int mf = 0; mf < 4; mf++)
#pragma unroll
    for (int r = 0; r < 4; r++) {
      int row = mt * 64 + mf * 16 + quad * 4 + r;
      size_t idx = (size_t)h * 1048576 + (size_t)row * 256 + col;
      float y = net[idx] + fmaxf(cm[mf][r], 0.f);
      tmp[idx] = y;
      cs += y;
      cq += y * y;
    }
  cs += __shfl_xor(cs, 16, 64); cs += __shfl_xor(cs, 32, 64);
  cq += __shfl_xor(cq, 16, 64); cq += __shfl_xor(cq, 32, 64);
  if (quad == 0) {
    atomicAdd(&stats[(h * 256 + col) * 2], cs);
    atomicAdd(&stats[(h * 256 + col) * 2 + 1], cq);
  }
}

// ---------------------------------------------------------------------------
// Pipelined MFMA flash attention.
// S-phase: split-f16 MFMA (R5 numerics, proven). PV: split-bf16 (R4, proven).
// Staging is register-prefetched: every global load is issued >=1 mfma-phase
// before its LDS write, so barrier vmcnt drains find data already arrived.
// Epilogue: y = net + O/l -> tmp, fused BN stats.
// Block 256 = 4 waves; wave wv owns q-rows [qt*64+wv*16, +16).
// MFMA maps (verified): A[m=ln][k=quad*8+j], B[n=ln][k=quad*8+j],
// C/D row=quad*4+r, col=ln.
// grid (16 q-tiles, 4 batch, 8 heads)
// ---------------------------------------------------------------------------
__global__ __launch_bounds__(256, 2) void k_attn(
    const _Float16* __restrict__ qhb, const _Float16* __restrict__ qlb,
    const _Float16* __restrict__ khb, const _Float16* __restrict__ klb,
    const short* __restrict__ vth, const short* __restrict__ vtl,
    const float* __restrict__ net, float* __restrict__ tmp,
    float* __restrict__ stats)
{
  // Overlaid LDS, 52,224 B (3 blocks/CU possible):
  //   Kh [0,8704) Kl [8704,17408)  -- S-phase
  //   Vh [0,17408) Vl [17408,34816) -- PV chunks (overlay K, time-disjoint)
  //   Ph [34816,43520) Pl [43520,52224) -- wave-private P
  __shared__ __align__(16) char smem[52224];
  _Float16 (*Kh)[LHS] = (_Float16(*)[LHS])(smem);
  _Float16 (*Kl)[LHS] = (_Float16(*)[LHS])(smem + 8704);
  short (*Vh)[LHS] = (short(*)[LHS])(smem);
  short (*Vl)[LHS] = (short(*)[LHS])(smem + 17408);
  short (*Ph)[LHS] = (short(*)[LHS])(smem + 34816);
  short (*Pl)[LHS] = (short(*)[LHS])(smem + 43520);

  const int qt = blockIdx.x, b = blockIdx.y, h = blockIdx.z;
  const int tid = threadIdx.x, wv = tid >> 6, lane = tid & 63;
  const int ln = lane & 15, quad = lane >> 4;

  // Q fragments once from global (A-layout, 16B contiguous per lane)
  const int qrow = qt * 64 + wv * 16 + ln;
  const size_t qoff = ((size_t)h * 4096 + b * 1024 + qrow) * 64;
  const h8 qh0 = *(const h8*)(qhb + qoff + quad * 8);
  const h8 qh1 = *(const h8*)(qhb + qoff + 32 + quad * 8);
  const h8 ql0 = *(const h8*)(qlb + qoff + quad * 8);
  const h8 ql1 = *(const h8*)(qlb + qoff + 32 + quad * 8);

  const _Float16* khg = khb + ((size_t)h * 4096 + b * 1024) * 64;
  const _Float16* klg = klb + ((size_t)h * 4096 + b * 1024) * 64;
  const short* vhg = vth + (size_t)(h * 4 + b) * 262144;   // [256 vcol][1024 s]
  const short* vlg = vtl + (size_t)(h * 4 + b) * 262144;

  // staging index decomposition (shared by K and V loops)
  const int kr0 = tid >> 3, fc0 = tid & 7;            // e = tid
  const int kr1 = (tid + 256) >> 3, fc1 = (tid + 256) & 7;

  f4 O[16];
#pragma unroll
  for (int nt = 0; nt < 16; nt++) O[nt] = (f4){0.f, 0.f, 0.f, 0.f};
  float m[4] = {-1e30f, -1e30f, -1e30f, -1e30f};
  float l[4] = {0.f, 0.f, 0.f, 0.f};

  // preload K(0) into regs
  h8 krh[2], krl[2];
  krh[0] = *(const h8*)&khg[kr0 * 64 + fc0 * 8];
  krh[1] = *(const h8*)&khg[kr1 * 64 + fc1 * 8];
  krl[0] = *(const h8*)&klg[kr0 * 64 + fc0 * 8];
  krl[1] = *(const h8*)&klg[kr1 * 64 + fc1 * 8];

  for (int kt = 0; kt < 16; kt++) {
    // write prefetched K regs -> LDS (region free: B6 of prev iter)
    *(h8*)&Kh[kr0][fc0 * 8] = krh[0];
    *(h8*)&Kh[kr1][fc1 * 8] = krh[1];
    *(h8*)&Kl[kr0][fc0 * 8] = krl[0];
    *(h8*)&Kl[kr1][fc1 * 8] = krl[1];
    // issue V chunk0 loads (consumed after B2)
    bf8 v0h[4], v0l[4];
#pragma unroll
    for (int i = 0; i < 4; i++) {
      int e = tid + i * 256;
      int vc = e >> 3, fc = e & 7;
      size_t g = (size_t)vc * 1024 + kt * 64 + fc * 8;
      v0h[i] = *(const bf8*)&vhg[g];
      v0l[i] = *(const bf8*)&vlg[g];
    }
    __syncthreads();   // B1: K visible

    // S-phase: 4 col-tiles of 16 keys; exact split w/ corr accumulator
    f4 s[4];
#pragma unroll
    for (int ct = 0; ct < 4; ct++) {
      h8 kh0 = *(const h8*)&Kh[ct * 16 + ln][quad * 8];
      h8 kh1 = *(const h8*)&Kh[ct * 16 + ln][32 + quad * 8];
      h8 kl0 = *(const h8*)&Kl[ct * 16 + ln][quad * 8];
      h8 kl1 = *(const h8*)&Kl[ct * 16 + ln][32 + quad * 8];
      f4 mn = (f4){0.f, 0.f, 0.f, 0.f};
      f4 cr = (f4){0.f, 0.f, 0.f, 0.f};
      mn = __builtin_amdgcn_mfma_f32_16x16x32_f16(qh0, kh0, mn, 0, 0, 0);
      mn = __builtin_amdgcn_mfma_f32_16x16x32_f16(qh1, kh1, mn, 0, 0, 0);
      cr = __builtin_amdgcn_mfma_f32_16x16x32_f16(qh0, kl0, cr, 0, 0, 0);
      cr = __builtin_amdgcn_mfma_f32_16x16x32_f16(qh1, kl1, cr, 0, 0, 0);
      cr = __builtin_amdgcn_mfma_f32_16x16x32_f16(ql0, kh0, cr, 0, 0, 0);
      cr = __builtin_amdgcn_mfma_f32_16x16x32_f16(ql1, kh1, cr, 0, 0, 0);
#pragma unroll
      for (int r = 0; r < 4; r++) s[ct][r] = (mn[r] + cr[r] * INV2048) * SCL;
    }

    // online softmax (R5 numerics, proven)
    float alpha[4];
#pragma unroll
    for (int r = 0; r < 4; r++) {
      float mx = fmaxf(fmaxf(s[0][r], s[1][r]), fmaxf(s[2][r], s[3][r]));
#pragma unroll
      for (int d = 1; d < 16; d <<= 1) mx = fmaxf(mx, __shfl_xor(mx, d, 64));
      float mn_ = fmaxf(m[r], mx);
      alpha[r] = __expf(m[r] - mn_);
      float ps = 0.f;
#pragma unroll
      for (int ct = 0; ct < 4; ct++) {
        float p = __expf(s[ct][r] - mn_);
        s[ct][r] = p;
        ps += p;
      }
#pragma unroll
      for (int d = 1; d < 16; d <<= 1) ps += __shfl_xor(ps, d, 64);
      l[r] = l[r] * alpha[r] + ps;
      m[r] = mn_;
    }
#pragma unroll
    for (int nt = 0; nt < 16; nt++)
#pragma unroll
      for (int r = 0; r < 4; r++) O[nt][r] *= alpha[r];

    // P hi/lo bf16 -> LDS (wave-private rows; same-wave DS ordering)
#pragma unroll
    for (int r = 0; r < 4; r++)
#pragma unroll
      for (int ct = 0; ct < 4; ct++) {
        float p = s[ct][r];
        short hi = f2bf(p);
        Ph[wv * 16 + quad * 4 + r][ct * 16 + ln] = hi;
        Pl[wv * 16 + quad * 4 + r][ct * 16 + ln] = f2bf(p - bf2f(hi));
      }
    bf8 ph0 = *(const bf8*)&Ph[wv * 16 + ln][quad * 8];
    bf8 ph1 = *(const bf8*)&Ph[wv * 16 + ln][32 + quad * 8];
    bf8 pl0 = *(const bf8*)&Pl[wv * 16 + ln][quad * 8];
    bf8 pl1 = *(const bf8*)&Pl[wv * 16 + ln][32 + quad * 8];
    __syncthreads();   // B2: all waves done reading K; V overlay safe

    // write V chunk0 (loads issued before B1 -> long since arrived)
#pragma unroll
    for (int i = 0; i < 4; i++) {
      int e = tid + i * 256;
      int vc = e >> 3, fc = e & 7;
      *(bf8*)&Vh[vc][fc * 8] = v0h[i];
      *(bf8*)&Vl[vc][fc * 8] = v0l[i];
    }
    // issue V chunk1 loads (consumed after B4)
    bf8 v1h[4], v1l[4];
#pragma unroll
    for (int i = 0; i < 4; i++) {
      int e = tid + i * 256;
      int vc = e >> 3, fc = e & 7;
      size_t g = (size_t)(128 + vc) * 1024 + kt * 64 + fc * 8;
      v1h[i] = *(const bf8*)&vhg[g];
      v1l[i] = *(const bf8*)&vlg[g];
    }
    __syncthreads();   // B3: V chunk0 visible

    // PV chunk0: vcols 0..127 (nt 0..7)
#pragma unroll
    for (int n2 = 0; n2 < 8; n2++) {
      bf8 vh0 = *(const bf8*)&Vh[n2 * 16 + ln][quad * 8];
      bf8 vh1 = *(const bf8*)&Vh[n2 * 16 + ln][32 + quad * 8];
      bf8 vl0 = *(const bf8*)&Vl[n2 * 16 + ln][quad * 8];
      bf8 vl1 = *(const bf8*)&Vl[n2 * 16 + ln][32 + quad * 8];
      O[n2] = __builtin_amdgcn_mfma_f32_16x16x32_bf16(ph0, vh0, O[n2], 0, 0, 0);
      O[n2] = __builtin_amdgcn_mfma_f32_16x16x32_bf16(ph1, vh1, O[n2], 0, 0, 0);
      O[n2] = __builtin_amdgcn_mfma_f32_16x16x32_bf16(ph0, vl0, O[n2], 0, 0, 0);
      O[n2] = __builtin_amdgcn_mfma_f32_16x16x32_bf16(ph1, vl1, O[n2], 0, 0, 0);
      O[n2] = __builtin_amdgcn_mfma_f32_16x16x32_bf16(pl0, vh0, O[n2], 0, 0, 0);
      O[n2] = __builtin_amdgcn_mfma_f32_16x16x32_bf16(pl1, vh1, O[n2], 0, 0, 0);
    }
    __syncthreads();   // B4: chunk0 reads done

    // write V chunk1; prefetch K(kt+1)
#pragma unroll
    for (int i = 0; i < 4; i++) {
      int e = tid + i * 256;
      int vc = e >> 3, fc = e & 7;
      *(bf8*)&Vh[vc][fc * 8] = v1h[i];
      *(bf8*)&Vl[vc][fc * 8] = v1l[i];
    }
    if (kt < 15) {
      krh[0] = *(const h8*)&khg[((kt + 1) * 64 + kr0) * 64 + fc0 * 8];
      krh[1] = *(const h8*)&khg[((kt + 1) * 64 + kr1) * 64 + fc1 * 8];
      krl[0] = *(const h8*)&klg[((kt + 1) * 64 + kr0) * 64 + fc0 * 8];
      krl[1] = *(const h8*)&klg[((kt + 1) * 64 + kr1) * 64 + fc1 * 8];
    }
    __syncthreads();   // B5: V chunk1 visible

    // PV chunk1: vcols 128..255 (nt 8..15)
#pragma unroll
    for (int n2 = 0; n2 < 8; n2++) {
      int nt = 8 + n2;
      bf8 vh0 = *(const bf8*)&Vh[n2 * 16 + ln][quad * 8];
      bf8 vh1 = *(const bf8*)&Vh[n2 * 16 + ln][32 + quad * 8];
      bf8 vl0 = *(const bf8*)&Vl[n2 * 16 + ln][quad * 8];
      bf8 vl1 = *(const bf8*)&Vl[n2 * 16 + ln][32 + quad * 8];
      O[nt] = __builtin_amdgcn_mfma_f32_16x16x32_bf16(ph0, vh0, O[nt], 0, 0, 0);
      O[nt] = __builtin_amdgcn_mfma_f32_16x16x32_bf16(ph1, vh1, O[nt], 0, 0, 0);
      O[nt] = __builtin_amdgcn_mfma_f32_16x16x32_bf16(ph0, vl0, O[nt], 0, 0, 0);
      O[nt] = __builtin_amdgcn_mfma_f32_16x16x32_bf16(ph1, vl1, O[nt], 0, 0, 0);
      O[nt] = __builtin_amdgcn_mfma_f32_16x16x32_bf16(pl0, vh0, O[nt], 0, 0, 0);
      O[nt] = __builtin_amdgcn_mfma_f32_16x16x32_bf16(pl1, vh1, O[nt], 0, 0, 0);
    }
    __syncthreads();   // B6: chunk1 reads done before next kt's K write
  }

  // epilogue: y = net + O/l -> tmp, fused BN stats
  float linv[4];
#pragma unroll
  for (int r = 0; r < 4; r++) linv[r] = 1.f / l[r];
  const size_t rbase = (size_t)h * 1048576 + (size_t)b * 262144;
#pragma unroll
  for (int nt = 0; nt < 16; nt++) {
    int c = nt * 16 + ln;
    float as = 0.f, aq = 0.f;
#pragma unroll
    for (int r = 0; r < 4; r++) {
      int row = qt * 64 + wv * 16 + quad * 4 + r;
      size_t idx = rbase + (size_t)row * 256 + c;
      float y = net[idx] + O[nt][r] * linv[r];
      tmp[idx] = y;
      as += y;
      aq += y * y;
    }
    as += __shfl_xor(as, 16, 64); as += __shfl_xor(as, 32, 64);
    aq += __shfl_xor(aq, 16, 64); aq += __shfl_xor(aq, 32, 64);
    if (quad == 0) {
      atomicAdd(&stats[(h * 256 + c) * 2], as);
      atomicAdd(&stats[(h * 256 + c) * 2 + 1], aq);
    }
  }
}

// ---------------------------------------------------------------------------
// BN apply: dst = (y - mean) * rsqrt(var+eps) * gamma + beta.
// transposed=1 writes d_out in [B,S,H,V] layout.
// ---------------------------------------------------------------------------
__global__ __launch_bounds__(256) void k_bnapply(
    const float* __restrict__ a,
    const float* __restrict__ stats,
    const float* __restrict__ gamma, const float* __restrict__ beta,
    float* __restrict__ dst, int t, int transposed)
{
  const int h = blockIdx.y, r0 = blockIdx.x * 64, c = threadIdx.x;
  float s  = stats[(h * 256 + c) * 2];
  float s2 = stats[(h * 256 + c) * 2 + 1];
  float mean = s * (1.f / 4096.f);
  float var  = s2 * (1.f / 4096.f) - mean * mean;
  float inv  = rsqrtf(var + EPSV);
  float g  = gamma[(h * TT + t) * 256 + c] * inv;
  float bt = beta[(h * TT + t) * 256 + c];
  const float* pa = a + (size_t)h * 1048576 + r0 * 256 + c;
  for (int r = 0; r < 64; r++) {
    float y = pa[r * 256];
    float o = (y - mean) * g + bt;
    int rg = r0 + r;
    if (transposed) dst[((size_t)rg * HH + h) * 256 + c] = o;
    else            dst[(size_t)h * 1048576 + rg * 256 + c] = o;
  }
}

// ---------------------------------------------------------------------------
extern "C" void kernel_launch(void* const* d_in, const int* in_sizes, int n_in,
                              void* d_out, int out_size, void* d_ws, size_t ws_size,
                              hipStream_t stream)
{
  const float* x   = (const float*)d_in[0];
  const float* Win = (const float*)d_in[1];
  const float* Wq  = (const float*)d_in[2];
  const float* Wk  = (const float*)d_in[3];
  const float* Wv  = (const float*)d_in[4];
  const float* Wd  = (const float*)d_in[5];
  const float* g1  = (const float*)d_in[6];
  const float* b1  = (const float*)d_in[7];
  const float* g2  = (const float*)d_in[8];
  const float* b2  = (const float*)d_in[9];
  float* out = (float*)d_out;
  float* ws  = (float*)d_ws;

  float* net   = ws;                       // H*BS*V fp32       =  8,388,608 f
  float* tmp   = net + 8388608;            // H*BS*V fp32       =  8,388,608 f
  float* stats = tmp + 8388608;            // 8 phases * H*V*2  =     32,768 f
  _Float16* qhb = (_Float16*)(stats + 32768);  // H*BS*64 f16   =  2,097,152 h
  _Float16* qlb = qhb + 2097152;
  _Float16* khb = qlb + 2097152;
  _Float16* klb = khb + 2097152;
  short* vth = (short*)(klb + 2097152);    // H*B*V*S bf16 hi   =  8,388,608 s
  short* vtl = vth + 8388608;              // H*B*V*S bf16 lo   =  8,388,608 s
  _Float16* wph = (_Float16*)(vtl + 8388608);  // prepped W hi  =  1,310,720 h
  _Float16* wpl = wph + 1310720;               // prepped W lo  =  1,310,720 h

  hipMemsetAsync(stats, 0, 8 * HH * VV * 2 * sizeof(float), stream);

  k_in_dense<<<dim3(64, 4), 256, 0, stream>>>(x, Win, net);

  for (int t = 0; t < TT; t++) {
    float* st1 = stats + (t * 2 + 0) * HH * VV * 2;
    float* st2 = stats + (t * 2 + 1) * HH * VV * 2;

    k_prep<<<dim3(10, 4, 8), 256, 0, stream>>>(Wq, Wk, Wv, Wd, wph, wpl, t);
    k_mm_qkv<<<dim3(64, 6, 8), 256, 0, stream>>>(net, wph, wpl,
                                                 qhb, qlb, khb, klb, vth, vtl);
    k_attn<<<dim3(16, 4, 8), 256, 0, stream>>>(qhb, qlb, khb, klb, vth, vtl,
                                               net, tmp, st1);
    k_bnapply<<<dim3(64, 8), 256, 0, stream>>>(tmp, st1, g1, b1, net, t, 0);

    k_mm_dense<<<dim3(64, 4, 8), 256, 0, stream>>>(net, wph, wpl, tmp, st2);

    if (t < TT - 1)
      k_bnapply<<<dim3(64, 8), 256, 0, stream>>>(tmp, st2, g2, b2, net, t, 0);
    else
      k_bnapply<<<dim3(64, 8), 256, 0, stream>>>(tmp, st2, g2, b2, out, t, 1);
  }
}